// Round 10
// baseline (262.772 us; speedup 1.0000x reference)
//
#include <hip/hip_runtime.h>
#include <hip/hip_fp16.h>

#define NV 50000
#define EE 650000
#define MM 3
#define NBUK 196       // buckets of 256 nodes: dst >> 8
#define PADCAP 2048    // per-bucket slack for 8-padding
#define CSRSTRIDE (EE + NBUK * PADCAP)
#define CHSZ 4096
#define NCH 159        // ceil(EE/CHSZ)
#define SEMBLK 586     // ceil(150000/256)

typedef __attribute__((ext_vector_type(8))) __bf16 bf16x8;
typedef __attribute__((ext_vector_type(8))) _Float16 f16x8;
typedef __attribute__((ext_vector_type(8))) unsigned short u16x8;
typedef __attribute__((ext_vector_type(4))) float f32x4;

__device__ __forceinline__ unsigned short f2bf(float f) {
    unsigned u = __builtin_bit_cast(unsigned, f);
    u += 0x7FFFu + ((u >> 16) & 1u);            // RTNE
    return (unsigned short)(u >> 16);
}
__device__ __forceinline__ bf16x8 zero8() {
    u16x8 u = {0,0,0,0,0,0,0,0};
    return __builtin_bit_cast(bf16x8, u);
}
__device__ __forceinline__ f16x8 zero8h() {
    u16x8 u = {0,0,0,0,0,0,0,0};
    return __builtin_bit_cast(f16x8, u);
}
__device__ __forceinline__ unsigned short f2h(float f) {
    return __builtin_bit_cast(unsigned short, __float2half(f));
}

// ---------------- K0: h->bf16 pack + weight transpose/convert (merged) ----------------
__global__ void prep_all(const float* __restrict__ h, const float* __restrict__ Wg,
                         const float* __restrict__ Ws1, unsigned* __restrict__ hb,
                         unsigned short* __restrict__ WT, unsigned short* __restrict__ WsT) {
    int idx = blockIdx.x * 256 + threadIdx.x;          // NV*64 + 4*16384 exact
    if (idx < NV * 64) {
        float2 f = *reinterpret_cast<const float2*>(h + (size_t)idx * 2);
        hb[idx] = ((unsigned)f2bf(f.x)) | (((unsigned)f2bf(f.y)) << 16);
    } else if (idx < NV * 64 + MM * 16384) {
        int r0 = idx - NV * 64;
        int m = r0 / 16384, r = r0 % 16384;
        int o = r >> 7, d = r & 127;
        WT[r0] = f2bf(Wg[m * 16384 + d * 128 + o]);
    } else {
        int r = idx - NV * 64 - MM * 16384;
        int j = r >> 7, d = r & 127;
        WsT[r] = f2h(Ws1[d * 128 + j]);
    }
}

// ---------------- K1: feat(f16-packed) = h @ W[m], + el, er ----------------
__global__ __launch_bounds__(256, 2) void gemm_feat(
    const unsigned short* __restrict__ hb, const unsigned short* __restrict__ WT,
    const float* __restrict__ attn_l, const float* __restrict__ attn_r,
    unsigned* __restrict__ featb, float* __restrict__ el, float* __restrict__ er) {
    const int m = blockIdx.y;
    const int tid = threadIdx.x;
    const int wave = tid >> 6, lane = tid & 63;
    const int lo = lane & 15, hi = lane >> 4;
    const int rowbase = blockIdx.x * 256 + wave * 64;
    const unsigned short* WTm = WT + m * 16384;

    f32x4 acc[4][8];
#pragma unroll
    for (int a = 0; a < 4; ++a)
#pragma unroll
        for (int b = 0; b < 8; ++b) acc[a][b] = (f32x4){0.f, 0.f, 0.f, 0.f};

#pragma unroll
    for (int kk = 0; kk < 4; ++kk) {
        bf16x8 bfrag[8];
#pragma unroll
        for (int ct = 0; ct < 8; ++ct)
            bfrag[ct] = *reinterpret_cast<const bf16x8*>(WTm + (ct * 16 + lo) * 128 + kk * 32 + hi * 8);
#pragma unroll
        for (int rt = 0; rt < 4; ++rt) {
            int row = rowbase + rt * 16 + lo;
            bf16x8 af = (row < NV)
                ? *reinterpret_cast<const bf16x8*>(hb + (size_t)row * 128 + kk * 32 + hi * 8)
                : zero8();
#pragma unroll
            for (int ct = 0; ct < 8; ++ct)
                acc[rt][ct] = __builtin_amdgcn_mfma_f32_16x16x32_bf16(af, bfrag[ct], acc[rt][ct], 0, 0, 0);
        }
    }

    float alv[8], arv[8];
#pragma unroll
    for (int ct = 0; ct < 8; ++ct) {
        alv[ct] = attn_l[m * 128 + ct * 16 + lo];
        arv[ct] = attn_r[m * 128 + ct * 16 + lo];
    }

#pragma unroll
    for (int rt = 0; rt < 4; ++rt) {
        float pl[4] = {0.f, 0.f, 0.f, 0.f}, pr[4] = {0.f, 0.f, 0.f, 0.f};
#pragma unroll
        for (int ct = 0; ct < 8; ++ct)
#pragma unroll
            for (int i = 0; i < 4; ++i) {
                pl[i] += acc[rt][ct][i] * alv[ct];
                pr[i] += acc[rt][ct][i] * arv[ct];
            }
#pragma unroll
        for (int s = 1; s < 16; s <<= 1)
#pragma unroll
            for (int i = 0; i < 4; ++i) {
                pl[i] += __shfl_xor(pl[i], s, 64);
                pr[i] += __shfl_xor(pr[i], s, 64);
            }
        int row0 = rowbase + rt * 16 + hi * 4;
        if (lo == 0) {
#pragma unroll
            for (int i = 0; i < 4; ++i)
                if (row0 + i < NV) {
                    el[m * NV + row0 + i] = pl[i];
                    er[m * NV + row0 + i] = pr[i];
                }
        }
        // f16 packed-pair store: cols (c, c+1), c = ct*16 + lo (even lo packs)
#pragma unroll
        for (int ct = 0; ct < 8; ++ct)
#pragma unroll
            for (int i = 0; i < 4; ++i) {
                float v = acc[rt][ct][i];
                float vp = __shfl_xor(v, 1, 64);     // partner col c^1
                int row = row0 + i;
                if (((lo & 1) == 0) && row < NV) {
                    unsigned pk = ((unsigned)f2h(v)) | (((unsigned)f2h(vp)) << 16);
                    featb[(size_t)(m * NV + row) * 64 + ct * 8 + (lo >> 1)] = pk;
                }
            }
    }
}

// ---------------- CSR build: atomic-free bucketed counting sort ----------------
__global__ __launch_bounds__(256) void hist_k(const int* __restrict__ edst,
                                              int* __restrict__ counts) {
    int m = blockIdx.y, c = blockIdx.x, tid = threadIdx.x;
    __shared__ int hsm[NBUK];
    if (tid < NBUK) hsm[tid] = 0;
    __syncthreads();
    int base = c * CHSZ;
#pragma unroll
    for (int i = 0; i < CHSZ / 256; ++i) {
        int e = base + i * 256 + tid;
        if (e < EE) {
            int d = edst[(size_t)m * EE + e];
            atomicAdd(&hsm[d >> 8], 1);
        }
    }
    __syncthreads();
    if (tid < NBUK) counts[(m * NCH + c) * NBUK + tid] = hsm[tid];
}

__global__ __launch_bounds__(1024) void scan_k(const int* __restrict__ counts,
                                               int* __restrict__ chunkpos,
                                               int* __restrict__ bstart) {
    int t = threadIdx.x;
    __shared__ int btot[MM * NBUK];
    if (t < MM * NBUK) {                               // 588 < 1024
        int m = t / NBUK, b = t % NBUK;
        int run = 0;
        for (int c = 0; c < NCH; ++c) {
            chunkpos[(m * NCH + c) * NBUK + b] = run;
            run += counts[(m * NCH + c) * NBUK + b];
        }
        btot[t] = run;
    }
    __syncthreads();
    if (t == 0) {
        for (int m = 0; m < MM; ++m) {
            int run = 0;
            for (int b = 0; b < NBUK; ++b) {
                bstart[m * NBUK + b] = run;
                run += btot[m * NBUK + b];
            }
        }
    }
}

__global__ __launch_bounds__(256) void scat1_k(const int* __restrict__ esrc,
                                               const int* __restrict__ edst,
                                               const int* __restrict__ chunkpos,
                                               const int* __restrict__ bstart,
                                               unsigned* __restrict__ staging) {
    int m = blockIdx.y, c = blockIdx.x, tid = threadIdx.x;
    __shared__ int cnt[NBUK];
    __shared__ int sofs[NBUK];
    if (tid < NBUK) {
        cnt[tid] = 0;
        sofs[tid] = bstart[m * NBUK + tid] + chunkpos[(m * NCH + c) * NBUK + tid];
    }
    __syncthreads();
    int base = c * CHSZ;
#pragma unroll
    for (int i = 0; i < CHSZ / 256; ++i) {
        int e = base + i * 256 + tid;
        if (e < EE) {
            int s = esrc[(size_t)m * EE + e];
            int d = edst[(size_t)m * EE + e];
            int b = d >> 8;
            int r = atomicAdd(&cnt[b], 1);
            staging[(size_t)m * EE + sofs[b] + r] =
                ((unsigned)(d & 255) << 16) | (unsigned)s;
        }
    }
}

// K5: per-bucket counting sort -> 8-padded two-plane CSR + per-node 1/den
__global__ __launch_bounds__(256) void bsort_k(const unsigned* __restrict__ staging,
                                               const int* __restrict__ bstart,
                                               const float* __restrict__ el,
                                               const float* __restrict__ er,
                                               unsigned* __restrict__ csr_off,
                                               float* __restrict__ csr_ex,
                                               int* __restrict__ start,
                                               int* __restrict__ deg,
                                               float* __restrict__ dinv) {
    int b = blockIdx.x, m = blockIdx.y, t = threadIdx.x;
    __shared__ int hsm[256];
    __shared__ int sc[256];
    __shared__ int cur[256];
    __shared__ float dsum[256];
    hsm[t] = 0;
    dsum[t] = 0.f;
    __syncthreads();
    int sbase = bstart[m * NBUK + b];
    int nseg = ((b == NBUK - 1) ? EE : bstart[m * NBUK + b + 1]) - sbase;
    const unsigned* sp = staging + (size_t)m * EE + sbase;
    for (int i = t; i < nseg; i += 256)
        atomicAdd(&hsm[sp[i] >> 16], 1);
    __syncthreads();
    int v = hsm[t];
    int pv = (v + 7) & ~7;                             // pad degree to multiple of 8
    sc[t] = pv;
    __syncthreads();
#pragma unroll
    for (int s = 1; s < 256; s <<= 1) {
        int add = (t >= s) ? sc[t - s] : 0;
        __syncthreads();
        sc[t] += add;
        __syncthreads();
    }
    int pexcl = sc[t] - pv;
    int pb = ((sbase + 7) & ~7) + b * PADCAP;          // 8-aligned bucket base
    cur[t] = pb + pexcl;
    int node = (b << 8) + t;
    if (node < NV) {
        deg[m * NV + node] = pv;
        start[m * NV + node] = pb + pexcl;
    }
    unsigned* offm = csr_off + (size_t)m * CSRSTRIDE;
    float* exm = csr_ex + (size_t)m * CSRSTRIDE;
    for (int k = v; k < pv; ++k) {                     // zero pad records
        offm[pb + pexcl + k] = 0;
        exm[pb + pexcl + k] = 0.f;
    }
    __syncthreads();
    int node0 = b << 8;
    for (int i = t; i < nseg; i += 256) {
        unsigned rec = sp[i];
        int dloc = rec >> 16;
        int s = rec & 0xFFFF;
        float x = el[m * NV + s] + er[m * NV + node0 + dloc];
        x = x > 0.f ? x : 0.2f * x;
        float ex = __expf(x);
        atomicAdd(&dsum[dloc], ex);                    // LDS float atomic
        int slot = atomicAdd(&cur[dloc], 1);
        offm[slot] = (unsigned)s * 256u;               // pre-scaled byte offset
        exm[slot] = ex;
    }
    __syncthreads();
    if (node < NV) dinv[m * NV + node] = 1.f / dsum[t];
}

// ---------------- K6: half-wave-per-node gather-aggregate + elu -> f16 z ----------------
// Inline-asm batched gathers: 8 global_load_dwordx2 in flight per chunk (forced MLP).
__global__ __launch_bounds__(256, 4) void aggregate_k(
    const unsigned* __restrict__ featb, const unsigned* __restrict__ csr_off,
    const float* __restrict__ csr_ex, const int* __restrict__ start,
    const int* __restrict__ deg, const float* __restrict__ dinv,
    const float* __restrict__ bias, unsigned* __restrict__ zh) {
    int wid = blockIdx.x * 4 + (threadIdx.x >> 6);     // wave 0..74999
    int gw = wid * 2 + ((threadIdx.x >> 5) & 1);       // node-slot 0..149999
    int sl = threadIdx.x & 31;
    int m = gw / NV;
    int st = start[gw];
    int dg = deg[gw];                                  // padded, multiple of 8
    const unsigned* offp = csr_off + (size_t)m * CSRSTRIDE + st;
    const float* xp = csr_ex + (size_t)m * CSRSTRIDE + st;
    unsigned laneb = (unsigned)(m * (NV * 256) + sl * 8);   // byte offset, fits 32-bit
    float a0 = 0.f, a1 = 0.f, a2 = 0.f, a3 = 0.f;
    for (int e0 = 0; e0 < dg; e0 += 8) {
        uint4 q0 = *reinterpret_cast<const uint4*>(offp + e0);
        uint4 q1 = *reinterpret_cast<const uint4*>(offp + e0 + 4);
        float4 x0 = *reinterpret_cast<const float4*>(xp + e0);
        float4 x1 = *reinterpret_cast<const float4*>(xp + e0 + 4);
        unsigned o0 = laneb + q0.x, o1 = laneb + q0.y, o2 = laneb + q0.z, o3 = laneb + q0.w;
        unsigned o4 = laneb + q1.x, o5 = laneb + q1.y, o6 = laneb + q1.z, o7 = laneb + q1.w;
        uint2 v0, v1, v2, v3, v4, v5, v6, v7;
        asm volatile(
            "global_load_dwordx2 %0, %8, %16\n\t"
            "global_load_dwordx2 %1, %9, %16\n\t"
            "global_load_dwordx2 %2, %10, %16\n\t"
            "global_load_dwordx2 %3, %11, %16\n\t"
            "global_load_dwordx2 %4, %12, %16\n\t"
            "global_load_dwordx2 %5, %13, %16\n\t"
            "global_load_dwordx2 %6, %14, %16\n\t"
            "global_load_dwordx2 %7, %15, %16\n\t"
            "s_waitcnt vmcnt(0)"
            : "=&v"(v0), "=&v"(v1), "=&v"(v2), "=&v"(v3),
              "=&v"(v4), "=&v"(v5), "=&v"(v6), "=&v"(v7)
            : "v"(o0), "v"(o1), "v"(o2), "v"(o3),
              "v"(o4), "v"(o5), "v"(o6), "v"(o7),
              "s"(featb)
            : "memory");
        float x[8] = {x0.x, x0.y, x0.z, x0.w, x1.x, x1.y, x1.z, x1.w};
        uint2 v[8] = {v0, v1, v2, v3, v4, v5, v6, v7};
#pragma unroll
        for (int i = 0; i < 8; ++i) {
            __half2 h0 = __builtin_bit_cast(__half2, v[i].x);
            __half2 h1 = __builtin_bit_cast(__half2, v[i].y);
            a0 = fmaf(x[i], __low2float(h0),  a0);
            a1 = fmaf(x[i], __high2float(h0), a1);
            a2 = fmaf(x[i], __low2float(h1),  a2);
            a3 = fmaf(x[i], __high2float(h1), a3);
        }
    }
    float inv = dinv[gw];
    int d0 = sl * 4;
    const float* bp = bias + m * 128 + d0;
    float z0 = a0 * inv + bp[0];
    float z1 = a1 * inv + bp[1];
    float z2 = a2 * inv + bp[2];
    float z3 = a3 * inv + bp[3];
    z0 = z0 > 0.f ? z0 : (__expf(z0) - 1.f);
    z1 = z1 > 0.f ? z1 : (__expf(z1) - 1.f);
    z2 = z2 > 0.f ? z2 : (__expf(z2) - 1.f);
    z3 = z3 > 0.f ? z3 : (__expf(z3) - 1.f);
    uint2 o;
    o.x = ((unsigned)f2h(z0)) | (((unsigned)f2h(z1)) << 16);
    o.y = ((unsigned)f2h(z2)) | (((unsigned)f2h(z3)) << 16);
    *reinterpret_cast<uint2*>(zh + (size_t)gw * 64 + sl * 2) = o;
}

// ---------------- K7: semantic attention scores (f16 MFMA GEMM + tanh + dot) ----------------
__global__ __launch_bounds__(256, 2) void semantic_k(
    const unsigned* __restrict__ zh, const unsigned short* __restrict__ WsT,
    const float* __restrict__ bs1, const float* __restrict__ Ws2,
    float* __restrict__ wpart) {
    const int tid = threadIdx.x;
    const int wave = tid >> 6, lane = tid & 63;
    const int lo = lane & 15, hi = lane >> 4;
    const int rowbase = blockIdx.x * 256 + wave * 64;

    f32x4 acc[4][8];
#pragma unroll
    for (int a = 0; a < 4; ++a)
#pragma unroll
        for (int b = 0; b < 8; ++b) acc[a][b] = (f32x4){0.f, 0.f, 0.f, 0.f};

#pragma unroll
    for (int kk = 0; kk < 4; ++kk) {
        f16x8 bfrag[8];
#pragma unroll
        for (int ct = 0; ct < 8; ++ct)
            bfrag[ct] = *reinterpret_cast<const f16x8*>(WsT + (ct * 16 + lo) * 128 + kk * 32 + hi * 8);
#pragma unroll
        for (int rt = 0; rt < 4; ++rt) {
            int row = rowbase + rt * 16 + lo;
            f16x8 af = (row < MM * NV)
                ? *reinterpret_cast<const f16x8*>(zh + (size_t)row * 64 + kk * 16 + hi * 2)
                : zero8h();
#pragma unroll
            for (int ct = 0; ct < 8; ++ct)
                acc[rt][ct] = __builtin_amdgcn_mfma_f32_16x16x32_f16(af, bfrag[ct], acc[rt][ct], 0, 0, 0);
        }
    }

    float w2v[8], b1v[8];
#pragma unroll
    for (int ct = 0; ct < 8; ++ct) {
        w2v[ct] = Ws2[ct * 16 + lo];
        b1v[ct] = bs1[ct * 16 + lo];
    }

    float t0 = 0.f, t1 = 0.f, t2 = 0.f;
#pragma unroll
    for (int rt = 0; rt < 4; ++rt) {
        int rbase = rowbase + rt * 16;
        if (rbase >= MM * NV) continue;        // wave-uniform
        int mm = rbase / NV;                   // 50000 % 16 == 0 -> tile is m-uniform
        float p = 0.f;
#pragma unroll
        for (int ct = 0; ct < 8; ++ct)
#pragma unroll
            for (int i = 0; i < 4; ++i) {
                float x = acc[rt][ct][i] + b1v[ct];
                x = fminf(fmaxf(x, -15.f), 15.f);
                float t = __expf(2.f * x);
                p += w2v[ct] * ((t - 1.f) / (t + 1.f));   // tanh
            }
#pragma unroll
        for (int s = 1; s < 64; s <<= 1) p += __shfl_xor(p, s, 64);
        if (mm == 0) t0 += p; else if (mm == 1) t1 += p; else t2 += p;
    }

    __shared__ float smw[4][3];
    if (lane == 0) { smw[wave][0] = t0; smw[wave][1] = t1; smw[wave][2] = t2; }
    __syncthreads();
    if (tid < 3)
        wpart[blockIdx.x * 4 + tid] =
            smw[0][tid] + smw[1][tid] + smw[2][tid] + smw[3][tid];
}

// ---------------- K8: reduce partials, beta = softmax(mean) ----------------
__global__ __launch_bounds__(64) void beta_k(const float* __restrict__ wpart,
                                             float* __restrict__ beta) {
    int lane = threadIdx.x;
    float t0 = 0.f, t1 = 0.f, t2 = 0.f;
    for (int b = lane; b < SEMBLK; b += 64) {
        t0 += wpart[b * 4 + 0];
        t1 += wpart[b * 4 + 1];
        t2 += wpart[b * 4 + 2];
    }
#pragma unroll
    for (int s = 1; s < 64; s <<= 1) {
        t0 += __shfl_xor(t0, s, 64);
        t1 += __shfl_xor(t1, s, 64);
        t2 += __shfl_xor(t2, s, 64);
    }
    if (lane == 0) {
        float w0 = t0 * (1.f / NV), w1 = t1 * (1.f / NV), w2 = t2 * (1.f / NV);
        float mx = fmaxf(w0, fmaxf(w1, w2));
        float e0 = __expf(w0 - mx), e1 = __expf(w1 - mx), e2 = __expf(w2 - mx);
        float inv = 1.f / (e0 + e1 + e2);
        beta[0] = e0 * inv; beta[1] = e1 * inv; beta[2] = e2 * inv;
    }
}

// ---------------- K9: out = sum_m beta[m] * z[m]  (f16 z input) ----------------
__global__ __launch_bounds__(256) void combine_k(const unsigned* __restrict__ zh,
                                                 const float* __restrict__ beta,
                                                 float* __restrict__ out) {
    int idx = blockIdx.x * 256 + threadIdx.x;          // 0..NV*32-1, 4 dims each
    float b0 = beta[0], b1 = beta[1], b2 = beta[2];
    uint2 u0 = *reinterpret_cast<const uint2*>(zh + (size_t)idx * 2);
    uint2 u1 = *reinterpret_cast<const uint2*>(zh + (size_t)NV * 64 + (size_t)idx * 2);
    uint2 u2 = *reinterpret_cast<const uint2*>(zh + (size_t)2 * NV * 64 + (size_t)idx * 2);
    float2 a0 = __half22float2(__builtin_bit_cast(__half2, u0.x));
    float2 a1 = __half22float2(__builtin_bit_cast(__half2, u0.y));
    float2 c0 = __half22float2(__builtin_bit_cast(__half2, u1.x));
    float2 c1 = __half22float2(__builtin_bit_cast(__half2, u1.y));
    float2 d0 = __half22float2(__builtin_bit_cast(__half2, u2.x));
    float2 d1 = __half22float2(__builtin_bit_cast(__half2, u2.y));
    float4 o;
    o.x = b0 * a0.x + b1 * c0.x + b2 * d0.x;
    o.y = b0 * a0.y + b1 * c0.y + b2 * d0.y;
    o.z = b0 * a1.x + b1 * c1.x + b2 * d1.x;
    o.w = b0 * a1.y + b1 * c1.y + b2 * d1.y;
    *reinterpret_cast<float4*>(out + (size_t)idx * 4) = o;
}

extern "C" void kernel_launch(void* const* d_in, const int* in_sizes, int n_in,
                              void* d_out, int out_size, void* d_ws, size_t ws_size,
                              hipStream_t stream) {
    const float* h      = (const float*)d_in[0];
    const int*   esrc   = (const int*)d_in[1];
    const int*   edst   = (const int*)d_in[2];
    const float* Wg     = (const float*)d_in[3];
    const float* attn_l = (const float*)d_in[4];
    const float* attn_r = (const float*)d_in[5];
    const float* bias   = (const float*)d_in[6];
    const float* Ws1    = (const float*)d_in[7];
    const float* bs1    = (const float*)d_in[8];
    const float* Ws2    = (const float*)d_in[9];
    float* out = (float*)d_out;

    char* w = (char*)d_ws;
    auto alloc = [&](size_t bytes) { char* p = w; w += (bytes + 255) & ~(size_t)255; return p; };
    unsigned short* WT   = (unsigned short*)alloc((size_t)MM * 128 * 128 * 2);
    unsigned short* WsT  = (unsigned short*)alloc((size_t)128 * 128 * 2);
    unsigned* hb    = (unsigned*)alloc((size_t)NV * 64 * 4);        // bf16-packed h
    unsigned* featb = (unsigned*)alloc((size_t)MM * NV * 64 * 4);   // f16-packed feat
    unsigned* zh    = (unsigned*)alloc((size_t)MM * NV * 64 * 4);   // f16-packed z
    float* el     = (float*)alloc((size_t)MM * NV * 4);
    float* er     = (float*)alloc((size_t)MM * NV * 4);
    float* dinv   = (float*)alloc((size_t)MM * NV * 4);
    int*   deg    = (int*)alloc((size_t)MM * NV * 4);
    int*   startb = (int*)alloc((size_t)MM * NV * 4);
    int*   counts = (int*)alloc((size_t)MM * NCH * NBUK * 4);
    int*   chunkpos = (int*)alloc((size_t)MM * NCH * NBUK * 4);
    int*   bstart = (int*)alloc((size_t)MM * NBUK * 4);
    unsigned* staging = (unsigned*)alloc((size_t)MM * EE * 4);
    unsigned* csr_off = (unsigned*)alloc((size_t)MM * CSRSTRIDE * 4);
    float*    csr_ex  = (float*)alloc((size_t)MM * CSRSTRIDE * 4);
    float* wpart  = (float*)alloc((size_t)SEMBLK * 4 * 4);
    float* beta   = (float*)alloc(256);

    hipLaunchKernelGGL(prep_all, dim3((NV * 64 + (MM + 1) * 16384) / 256), dim3(256), 0, stream,
                       h, Wg, Ws1, hb, WT, WsT);
    hipLaunchKernelGGL(gemm_feat, dim3(196, MM), dim3(256), 0, stream,
                       (const unsigned short*)hb, WT, attn_l, attn_r, featb, el, er);
    // atomic-free CSR build (196 buckets x 256 nodes)
    hipLaunchKernelGGL(hist_k, dim3(NCH, MM), dim3(256), 0, stream, edst, counts);
    hipLaunchKernelGGL(scan_k, dim3(1), dim3(1024), 0, stream, counts, chunkpos, bstart);
    hipLaunchKernelGGL(scat1_k, dim3(NCH, MM), dim3(256), 0, stream,
                       esrc, edst, chunkpos, bstart, staging);
    hipLaunchKernelGGL(bsort_k, dim3(NBUK, MM), dim3(256), 0, stream,
                       staging, bstart, el, er, csr_off, csr_ex, startb, deg, dinv);
    // aggregate (2 nodes per wave, asm-batched gathers)
    hipLaunchKernelGGL(aggregate_k, dim3((MM * NV) / 8), dim3(256), 0, stream,
                       featb, csr_off, csr_ex, startb, deg, dinv, bias, zh);
    // semantic attention (f16 MFMA)
    hipLaunchKernelGGL(semantic_k, dim3(SEMBLK), dim3(256), 0, stream,
                       zh, WsT, bs1, Ws2, wpart);
    hipLaunchKernelGGL(beta_k, dim3(1), dim3(64), 0, stream, wpart, beta);
    // combine: NV*32 threads, 4 dims each
    hipLaunchKernelGGL(combine_k, dim3(6250), dim3(256), 0, stream, zh, beta, out);
}

// Round 11
// 212.920 us; speedup vs baseline: 1.2341x; 1.2341x over previous
//
#include <hip/hip_runtime.h>
#include <hip/hip_fp16.h>

#define NV 50000
#define EE 650000
#define MM 3
#define NBUK 196       // buckets of 256 nodes: dst >> 8
#define PADCAP 2048    // per-bucket slack for 8-padding
#define CSRSTRIDE (EE + NBUK * PADCAP)
#define CHSZ 4096
#define NCH 159        // ceil(EE/CHSZ)
#define SEMBLK 586     // ceil(150000/256)

typedef __attribute__((ext_vector_type(8))) __bf16 bf16x8;
typedef __attribute__((ext_vector_type(8))) _Float16 f16x8;
typedef __attribute__((ext_vector_type(8))) unsigned short u16x8;
typedef __attribute__((ext_vector_type(4))) float f32x4;

__device__ __forceinline__ unsigned short f2bf(float f) {
    unsigned u = __builtin_bit_cast(unsigned, f);
    u += 0x7FFFu + ((u >> 16) & 1u);            // RTNE
    return (unsigned short)(u >> 16);
}
__device__ __forceinline__ bf16x8 zero8() {
    u16x8 u = {0,0,0,0,0,0,0,0};
    return __builtin_bit_cast(bf16x8, u);
}
__device__ __forceinline__ f16x8 zero8h() {
    u16x8 u = {0,0,0,0,0,0,0,0};
    return __builtin_bit_cast(f16x8, u);
}
__device__ __forceinline__ unsigned short f2h(float f) {
    return __builtin_bit_cast(unsigned short, __float2half(f));
}

// ---------------- K0: h->bf16 pack + weight transpose/convert (merged) ----------------
__global__ void prep_all(const float* __restrict__ h, const float* __restrict__ Wg,
                         const float* __restrict__ Ws1, unsigned* __restrict__ hb,
                         unsigned short* __restrict__ WT, unsigned short* __restrict__ WsT) {
    int idx = blockIdx.x * 256 + threadIdx.x;          // NV*64 + 4*16384 exact
    if (idx < NV * 64) {
        float2 f = *reinterpret_cast<const float2*>(h + (size_t)idx * 2);
        hb[idx] = ((unsigned)f2bf(f.x)) | (((unsigned)f2bf(f.y)) << 16);
    } else if (idx < NV * 64 + MM * 16384) {
        int r0 = idx - NV * 64;
        int m = r0 / 16384, r = r0 % 16384;
        int o = r >> 7, d = r & 127;
        WT[r0] = f2bf(Wg[m * 16384 + d * 128 + o]);
    } else {
        int r = idx - NV * 64 - MM * 16384;
        int j = r >> 7, d = r & 127;
        WsT[r] = f2h(Ws1[d * 128 + j]);
    }
}

// ---------------- K1: feat(f16-packed) = h @ W[m], + el, er ----------------
__global__ __launch_bounds__(256, 2) void gemm_feat(
    const unsigned short* __restrict__ hb, const unsigned short* __restrict__ WT,
    const float* __restrict__ attn_l, const float* __restrict__ attn_r,
    unsigned* __restrict__ featb, float* __restrict__ el, float* __restrict__ er) {
    const int m = blockIdx.y;
    const int tid = threadIdx.x;
    const int wave = tid >> 6, lane = tid & 63;
    const int lo = lane & 15, hi = lane >> 4;
    const int rowbase = blockIdx.x * 256 + wave * 64;
    const unsigned short* WTm = WT + m * 16384;

    f32x4 acc[4][8];
#pragma unroll
    for (int a = 0; a < 4; ++a)
#pragma unroll
        for (int b = 0; b < 8; ++b) acc[a][b] = (f32x4){0.f, 0.f, 0.f, 0.f};

#pragma unroll
    for (int kk = 0; kk < 4; ++kk) {
        bf16x8 bfrag[8];
#pragma unroll
        for (int ct = 0; ct < 8; ++ct)
            bfrag[ct] = *reinterpret_cast<const bf16x8*>(WTm + (ct * 16 + lo) * 128 + kk * 32 + hi * 8);
#pragma unroll
        for (int rt = 0; rt < 4; ++rt) {
            int row = rowbase + rt * 16 + lo;
            bf16x8 af = (row < NV)
                ? *reinterpret_cast<const bf16x8*>(hb + (size_t)row * 128 + kk * 32 + hi * 8)
                : zero8();
#pragma unroll
            for (int ct = 0; ct < 8; ++ct)
                acc[rt][ct] = __builtin_amdgcn_mfma_f32_16x16x32_bf16(af, bfrag[ct], acc[rt][ct], 0, 0, 0);
        }
    }

    float alv[8], arv[8];
#pragma unroll
    for (int ct = 0; ct < 8; ++ct) {
        alv[ct] = attn_l[m * 128 + ct * 16 + lo];
        arv[ct] = attn_r[m * 128 + ct * 16 + lo];
    }

#pragma unroll
    for (int rt = 0; rt < 4; ++rt) {
        float pl[4] = {0.f, 0.f, 0.f, 0.f}, pr[4] = {0.f, 0.f, 0.f, 0.f};
#pragma unroll
        for (int ct = 0; ct < 8; ++ct)
#pragma unroll
            for (int i = 0; i < 4; ++i) {
                pl[i] += acc[rt][ct][i] * alv[ct];
                pr[i] += acc[rt][ct][i] * arv[ct];
            }
#pragma unroll
        for (int s = 1; s < 16; s <<= 1)
#pragma unroll
            for (int i = 0; i < 4; ++i) {
                pl[i] += __shfl_xor(pl[i], s, 64);
                pr[i] += __shfl_xor(pr[i], s, 64);
            }
        int row0 = rowbase + rt * 16 + hi * 4;
        if (lo == 0) {
#pragma unroll
            for (int i = 0; i < 4; ++i)
                if (row0 + i < NV) {
                    el[m * NV + row0 + i] = pl[i];
                    er[m * NV + row0 + i] = pr[i];
                }
        }
        // f16 packed-pair store: cols (c, c+1), c = ct*16 + lo (even lo packs)
#pragma unroll
        for (int ct = 0; ct < 8; ++ct)
#pragma unroll
            for (int i = 0; i < 4; ++i) {
                float v = acc[rt][ct][i];
                float vp = __shfl_xor(v, 1, 64);     // partner col c^1
                int row = row0 + i;
                if (((lo & 1) == 0) && row < NV) {
                    unsigned pk = ((unsigned)f2h(v)) | (((unsigned)f2h(vp)) << 16);
                    featb[(size_t)(m * NV + row) * 64 + ct * 8 + (lo >> 1)] = pk;
                }
            }
    }
}

// ---------------- CSR build: atomic-free bucketed counting sort ----------------
__global__ __launch_bounds__(256) void hist_k(const int* __restrict__ edst,
                                              int* __restrict__ counts) {
    int m = blockIdx.y, c = blockIdx.x, tid = threadIdx.x;
    __shared__ int hsm[NBUK];
    if (tid < NBUK) hsm[tid] = 0;
    __syncthreads();
    int base = c * CHSZ;
#pragma unroll
    for (int i = 0; i < CHSZ / 256; ++i) {
        int e = base + i * 256 + tid;
        if (e < EE) {
            int d = edst[(size_t)m * EE + e];
            atomicAdd(&hsm[d >> 8], 1);
        }
    }
    __syncthreads();
    if (tid < NBUK) counts[(m * NCH + c) * NBUK + tid] = hsm[tid];
}

// P1: parallel exclusive scan over chunks for each (m,bucket) — 588 blocks
__global__ __launch_bounds__(256) void scanP1_k(const int* __restrict__ counts,
                                                int* __restrict__ chunkpos,
                                                int* __restrict__ btot) {
    int b = blockIdx.x, m = blockIdx.y, t = threadIdx.x;
    __shared__ int sm[256];
    int v = (t < NCH) ? counts[(m * NCH + t) * NBUK + b] : 0;
    sm[t] = v;
    __syncthreads();
#pragma unroll
    for (int s = 1; s < 256; s <<= 1) {
        int add = (t >= s) ? sm[t - s] : 0;
        __syncthreads();
        sm[t] += add;
        __syncthreads();
    }
    if (t < NCH) chunkpos[(m * NCH + t) * NBUK + b] = sm[t] - v;   // exclusive
    if (t == 0) btot[m * NBUK + b] = sm[255];                      // total
}

// P2: per-m exclusive scan over 196 buckets — 3 blocks
__global__ __launch_bounds__(256) void scanP2_k(const int* __restrict__ btot,
                                                int* __restrict__ bstart) {
    int m = blockIdx.x, t = threadIdx.x;
    __shared__ int sm[256];
    int v = (t < NBUK) ? btot[m * NBUK + t] : 0;
    sm[t] = v;
    __syncthreads();
#pragma unroll
    for (int s = 1; s < 256; s <<= 1) {
        int add = (t >= s) ? sm[t - s] : 0;
        __syncthreads();
        sm[t] += add;
        __syncthreads();
    }
    if (t < NBUK) bstart[m * NBUK + t] = sm[t] - v;                // exclusive
}

__global__ __launch_bounds__(256) void scat1_k(const int* __restrict__ esrc,
                                               const int* __restrict__ edst,
                                               const int* __restrict__ chunkpos,
                                               const int* __restrict__ bstart,
                                               unsigned* __restrict__ staging) {
    int m = blockIdx.y, c = blockIdx.x, tid = threadIdx.x;
    __shared__ int cnt[NBUK];
    __shared__ int sofs[NBUK];
    if (tid < NBUK) {
        cnt[tid] = 0;
        sofs[tid] = bstart[m * NBUK + tid] + chunkpos[(m * NCH + c) * NBUK + tid];
    }
    __syncthreads();
    int base = c * CHSZ;
#pragma unroll
    for (int i = 0; i < CHSZ / 256; ++i) {
        int e = base + i * 256 + tid;
        if (e < EE) {
            int s = esrc[(size_t)m * EE + e];
            int d = edst[(size_t)m * EE + e];
            int b = d >> 8;
            int r = atomicAdd(&cnt[b], 1);
            staging[(size_t)m * EE + sofs[b] + r] =
                ((unsigned)(d & 255) << 16) | (unsigned)s;
        }
    }
}

// K5: per-bucket counting sort -> 8-padded CSR (f16 ex << 16 | src), deg, start, 1/den
__global__ __launch_bounds__(256) void bsort_k(const unsigned* __restrict__ staging,
                                               const int* __restrict__ bstart,
                                               const float* __restrict__ el,
                                               const float* __restrict__ er,
                                               unsigned* __restrict__ csr,
                                               int* __restrict__ start,
                                               int* __restrict__ deg,
                                               float* __restrict__ dinv) {
    int b = blockIdx.x, m = blockIdx.y, t = threadIdx.x;
    __shared__ int hsm[256];
    __shared__ int sc[256];
    __shared__ int cur[256];
    __shared__ float dsum[256];
    hsm[t] = 0;
    dsum[t] = 0.f;
    __syncthreads();
    int sbase = bstart[m * NBUK + b];
    int nseg = ((b == NBUK - 1) ? EE : bstart[m * NBUK + b + 1]) - sbase;
    const unsigned* sp = staging + (size_t)m * EE + sbase;
    for (int i = t; i < nseg; i += 256)
        atomicAdd(&hsm[sp[i] >> 16], 1);
    __syncthreads();
    int v = hsm[t];
    int pv = (v + 7) & ~7;                             // pad degree to multiple of 8
    sc[t] = pv;
    __syncthreads();
#pragma unroll
    for (int s = 1; s < 256; s <<= 1) {
        int add = (t >= s) ? sc[t - s] : 0;
        __syncthreads();
        sc[t] += add;
        __syncthreads();
    }
    int pexcl = sc[t] - pv;
    int pb = ((sbase + 7) & ~7) + b * PADCAP;          // 8-aligned bucket base
    cur[t] = pb + pexcl;
    int node = (b << 8) + t;
    if (node < NV) {
        deg[m * NV + node] = pv;
        start[m * NV + node] = pb + pexcl;
    }
    unsigned* cpm = csr + (size_t)m * CSRSTRIDE;
    for (int k = v; k < pv; ++k) cpm[pb + pexcl + k] = 0;   // zero-ex pad records
    __syncthreads();
    int node0 = b << 8;
    for (int i = t; i < nseg; i += 256) {
        unsigned rec = sp[i];
        int dloc = rec >> 16;
        int s = rec & 0xFFFF;
        float x = el[m * NV + s] + er[m * NV + node0 + dloc];
        x = x > 0.f ? x : 0.2f * x;
        float ex = __expf(x);
        atomicAdd(&dsum[dloc], ex);                    // LDS float atomic
        int slot = atomicAdd(&cur[dloc], 1);
        cpm[slot] = ((unsigned)f2h(ex) << 16) | (unsigned)s;
    }
    __syncthreads();
    if (node < NV) dinv[m * NV + node] = 1.f / dsum[t];
}

// ---------------- K6: half-wave-per-node gather-aggregate + elu -> f16 z ----------------
// padded CSR: dg % 8 == 0 -> no tail; uint4 record loads; precomputed 1/den.
__global__ __launch_bounds__(256, 4) void aggregate_k(
    const unsigned* __restrict__ featb, const unsigned* __restrict__ csr,
    const int* __restrict__ start, const int* __restrict__ deg,
    const float* __restrict__ dinv, const float* __restrict__ bias,
    unsigned* __restrict__ zh) {
    int wid = blockIdx.x * 4 + (threadIdx.x >> 6);     // wave 0..74999
    int gw = wid * 2 + ((threadIdx.x >> 5) & 1);       // node-slot 0..149999
    int sl = threadIdx.x & 31;
    int m = gw / NV;
    int st = start[gw];
    int dg = deg[gw];                                  // padded, multiple of 8
    const unsigned* pp = csr + (size_t)m * CSRSTRIDE + st;
    const unsigned* fb = featb + (size_t)m * NV * 64 + sl * 2;
    float a0 = 0.f, a1 = 0.f, a2 = 0.f, a3 = 0.f;
    for (int e0 = 0; e0 < dg; e0 += 8) {
        uint4 r0 = *reinterpret_cast<const uint4*>(pp + e0);
        uint4 r1 = *reinterpret_cast<const uint4*>(pp + e0 + 4);
        unsigned p[8] = {r0.x, r0.y, r0.z, r0.w, r1.x, r1.y, r1.z, r1.w};
        uint2 v[8];
#pragma unroll
        for (int i = 0; i < 8; ++i) {
            unsigned off = (p[i] & 0xFFFFu) << 6;      // 32-bit element offset
            v[i] = *reinterpret_cast<const uint2*>(fb + off);
        }
#pragma unroll
        for (int i = 0; i < 8; ++i) {
            float x = __half2float(__builtin_bit_cast(__half, (unsigned short)(p[i] >> 16)));
            __half2 h0 = __builtin_bit_cast(__half2, v[i].x);
            __half2 h1 = __builtin_bit_cast(__half2, v[i].y);
            a0 = fmaf(x, __low2float(h0),  a0);
            a1 = fmaf(x, __high2float(h0), a1);
            a2 = fmaf(x, __low2float(h1),  a2);
            a3 = fmaf(x, __high2float(h1), a3);
        }
    }
    float inv = dinv[gw];
    int d0 = sl * 4;
    const float* bp = bias + m * 128 + d0;
    float z0 = a0 * inv + bp[0];
    float z1 = a1 * inv + bp[1];
    float z2 = a2 * inv + bp[2];
    float z3 = a3 * inv + bp[3];
    z0 = z0 > 0.f ? z0 : (__expf(z0) - 1.f);
    z1 = z1 > 0.f ? z1 : (__expf(z1) - 1.f);
    z2 = z2 > 0.f ? z2 : (__expf(z2) - 1.f);
    z3 = z3 > 0.f ? z3 : (__expf(z3) - 1.f);
    uint2 o;
    o.x = ((unsigned)f2h(z0)) | (((unsigned)f2h(z1)) << 16);
    o.y = ((unsigned)f2h(z2)) | (((unsigned)f2h(z3)) << 16);
    *reinterpret_cast<uint2*>(zh + (size_t)gw * 64 + sl * 2) = o;
}

// ---------------- K7: semantic attention scores (f16 MFMA GEMM + tanh + dot) ----------------
__global__ __launch_bounds__(256, 2) void semantic_k(
    const unsigned* __restrict__ zh, const unsigned short* __restrict__ WsT,
    const float* __restrict__ bs1, const float* __restrict__ Ws2,
    float* __restrict__ wpart) {
    const int tid = threadIdx.x;
    const int wave = tid >> 6, lane = tid & 63;
    const int lo = lane & 15, hi = lane >> 4;
    const int rowbase = blockIdx.x * 256 + wave * 64;

    f32x4 acc[4][8];
#pragma unroll
    for (int a = 0; a < 4; ++a)
#pragma unroll
        for (int b = 0; b < 8; ++b) acc[a][b] = (f32x4){0.f, 0.f, 0.f, 0.f};

#pragma unroll
    for (int kk = 0; kk < 4; ++kk) {
        f16x8 bfrag[8];
#pragma unroll
        for (int ct = 0; ct < 8; ++ct)
            bfrag[ct] = *reinterpret_cast<const f16x8*>(WsT + (ct * 16 + lo) * 128 + kk * 32 + hi * 8);
#pragma unroll
        for (int rt = 0; rt < 4; ++rt) {
            int row = rowbase + rt * 16 + lo;
            f16x8 af = (row < MM * NV)
                ? *reinterpret_cast<const f16x8*>(zh + (size_t)row * 64 + kk * 16 + hi * 2)
                : zero8h();
#pragma unroll
            for (int ct = 0; ct < 8; ++ct)
                acc[rt][ct] = __builtin_amdgcn_mfma_f32_16x16x32_f16(af, bfrag[ct], acc[rt][ct], 0, 0, 0);
        }
    }

    float w2v[8], b1v[8];
#pragma unroll
    for (int ct = 0; ct < 8; ++ct) {
        w2v[ct] = Ws2[ct * 16 + lo];
        b1v[ct] = bs1[ct * 16 + lo];
    }

    float t0 = 0.f, t1 = 0.f, t2 = 0.f;
#pragma unroll
    for (int rt = 0; rt < 4; ++rt) {
        int rbase = rowbase + rt * 16;
        if (rbase >= MM * NV) continue;        // wave-uniform
        int mm = rbase / NV;                   // 50000 % 16 == 0 -> tile is m-uniform
        float p = 0.f;
#pragma unroll
        for (int ct = 0; ct < 8; ++ct)
#pragma unroll
            for (int i = 0; i < 4; ++i) {
                float x = acc[rt][ct][i] + b1v[ct];
                x = fminf(fmaxf(x, -15.f), 15.f);
                float t = __expf(2.f * x);
                p += w2v[ct] * ((t - 1.f) / (t + 1.f));   // tanh
            }
#pragma unroll
        for (int s = 1; s < 64; s <<= 1) p += __shfl_xor(p, s, 64);
        if (mm == 0) t0 += p; else if (mm == 1) t1 += p; else t2 += p;
    }

    __shared__ float smw[4][3];
    if (lane == 0) { smw[wave][0] = t0; smw[wave][1] = t1; smw[wave][2] = t2; }
    __syncthreads();
    if (tid < 3)
        wpart[blockIdx.x * 4 + tid] =
            smw[0][tid] + smw[1][tid] + smw[2][tid] + smw[3][tid];
}

// ---------------- K8: reduce partials, beta = softmax(mean) ----------------
__global__ __launch_bounds__(64) void beta_k(const float* __restrict__ wpart,
                                             float* __restrict__ beta) {
    int lane = threadIdx.x;
    float t0 = 0.f, t1 = 0.f, t2 = 0.f;
    for (int b = lane; b < SEMBLK; b += 64) {
        t0 += wpart[b * 4 + 0];
        t1 += wpart[b * 4 + 1];
        t2 += wpart[b * 4 + 2];
    }
#pragma unroll
    for (int s = 1; s < 64; s <<= 1) {
        t0 += __shfl_xor(t0, s, 64);
        t1 += __shfl_xor(t1, s, 64);
        t2 += __shfl_xor(t2, s, 64);
    }
    if (lane == 0) {
        float w0 = t0 * (1.f / NV), w1 = t1 * (1.f / NV), w2 = t2 * (1.f / NV);
        float mx = fmaxf(w0, fmaxf(w1, w2));
        float e0 = __expf(w0 - mx), e1 = __expf(w1 - mx), e2 = __expf(w2 - mx);
        float inv = 1.f / (e0 + e1 + e2);
        beta[0] = e0 * inv; beta[1] = e1 * inv; beta[2] = e2 * inv;
    }
}

// ---------------- K9: out = sum_m beta[m] * z[m]  (f16 z input) ----------------
__global__ __launch_bounds__(256) void combine_k(const unsigned* __restrict__ zh,
                                                 const float* __restrict__ beta,
                                                 float* __restrict__ out) {
    int idx = blockIdx.x * 256 + threadIdx.x;          // 0..NV*32-1, 4 dims each
    float b0 = beta[0], b1 = beta[1], b2 = beta[2];
    uint2 u0 = *reinterpret_cast<const uint2*>(zh + (size_t)idx * 2);
    uint2 u1 = *reinterpret_cast<const uint2*>(zh + (size_t)NV * 64 + (size_t)idx * 2);
    uint2 u2 = *reinterpret_cast<const uint2*>(zh + (size_t)2 * NV * 64 + (size_t)idx * 2);
    float2 a0 = __half22float2(__builtin_bit_cast(__half2, u0.x));
    float2 a1 = __half22float2(__builtin_bit_cast(__half2, u0.y));
    float2 c0 = __half22float2(__builtin_bit_cast(__half2, u1.x));
    float2 c1 = __half22float2(__builtin_bit_cast(__half2, u1.y));
    float2 d0 = __half22float2(__builtin_bit_cast(__half2, u2.x));
    float2 d1 = __half22float2(__builtin_bit_cast(__half2, u2.y));
    float4 o;
    o.x = b0 * a0.x + b1 * c0.x + b2 * d0.x;
    o.y = b0 * a0.y + b1 * c0.y + b2 * d0.y;
    o.z = b0 * a1.x + b1 * c1.x + b2 * d1.x;
    o.w = b0 * a1.y + b1 * c1.y + b2 * d1.y;
    *reinterpret_cast<float4*>(out + (size_t)idx * 4) = o;
}

extern "C" void kernel_launch(void* const* d_in, const int* in_sizes, int n_in,
                              void* d_out, int out_size, void* d_ws, size_t ws_size,
                              hipStream_t stream) {
    const float* h      = (const float*)d_in[0];
    const int*   esrc   = (const int*)d_in[1];
    const int*   edst   = (const int*)d_in[2];
    const float* Wg     = (const float*)d_in[3];
    const float* attn_l = (const float*)d_in[4];
    const float* attn_r = (const float*)d_in[5];
    const float* bias   = (const float*)d_in[6];
    const float* Ws1    = (const float*)d_in[7];
    const float* bs1    = (const float*)d_in[8];
    const float* Ws2    = (const float*)d_in[9];
    float* out = (float*)d_out;

    char* w = (char*)d_ws;
    auto alloc = [&](size_t bytes) { char* p = w; w += (bytes + 255) & ~(size_t)255; return p; };
    unsigned short* WT   = (unsigned short*)alloc((size_t)MM * 128 * 128 * 2);
    unsigned short* WsT  = (unsigned short*)alloc((size_t)128 * 128 * 2);
    unsigned* hb    = (unsigned*)alloc((size_t)NV * 64 * 4);        // bf16-packed h
    unsigned* featb = (unsigned*)alloc((size_t)MM * NV * 64 * 4);   // f16-packed feat
    unsigned* zh    = (unsigned*)alloc((size_t)MM * NV * 64 * 4);   // f16-packed z
    float* el     = (float*)alloc((size_t)MM * NV * 4);
    float* er     = (float*)alloc((size_t)MM * NV * 4);
    float* dinv   = (float*)alloc((size_t)MM * NV * 4);
    int*   deg    = (int*)alloc((size_t)MM * NV * 4);
    int*   startb = (int*)alloc((size_t)MM * NV * 4);
    int*   counts = (int*)alloc((size_t)MM * NCH * NBUK * 4);
    int*   chunkpos = (int*)alloc((size_t)MM * NCH * NBUK * 4);
    int*   btot   = (int*)alloc((size_t)MM * NBUK * 4);
    int*   bstart = (int*)alloc((size_t)MM * NBUK * 4);
    unsigned* staging = (unsigned*)alloc((size_t)MM * EE * 4);
    unsigned* csr     = (unsigned*)alloc((size_t)MM * CSRSTRIDE * 4);
    float* wpart  = (float*)alloc((size_t)SEMBLK * 4 * 4);
    float* beta   = (float*)alloc(256);

    hipLaunchKernelGGL(prep_all, dim3((NV * 64 + (MM + 1) * 16384) / 256), dim3(256), 0, stream,
                       h, Wg, Ws1, hb, WT, WsT);
    hipLaunchKernelGGL(gemm_feat, dim3(196, MM), dim3(256), 0, stream,
                       (const unsigned short*)hb, WT, attn_l, attn_r, featb, el, er);
    // atomic-free CSR build (196 buckets x 256 nodes), parallel scans
    hipLaunchKernelGGL(hist_k, dim3(NCH, MM), dim3(256), 0, stream, edst, counts);
    hipLaunchKernelGGL(scanP1_k, dim3(NBUK, MM), dim3(256), 0, stream, counts, chunkpos, btot);
    hipLaunchKernelGGL(scanP2_k, dim3(MM), dim3(256), 0, stream, btot, bstart);
    hipLaunchKernelGGL(scat1_k, dim3(NCH, MM), dim3(256), 0, stream,
                       esrc, edst, chunkpos, bstart, staging);
    hipLaunchKernelGGL(bsort_k, dim3(NBUK, MM), dim3(256), 0, stream,
                       staging, bstart, el, er, csr, startb, deg, dinv);
    // aggregate (2 nodes per wave, padded CSR, round-8 best form)
    hipLaunchKernelGGL(aggregate_k, dim3((MM * NV) / 8), dim3(256), 0, stream,
                       featb, csr, startb, deg, dinv, bias, zh);
    // semantic attention (f16 MFMA)
    hipLaunchKernelGGL(semantic_k, dim3(SEMBLK), dim3(256), 0, stream,
                       zh, WsT, bs1, Ws2, wpart);
    hipLaunchKernelGGL(beta_k, dim3(1), dim3(64), 0, stream, wpart, beta);
    // combine: NV*32 threads, 4 dims each
    hipLaunchKernelGGL(combine_k, dim3(6250), dim3(256), 0, stream, zh, beta, out);
}